// Round 11
// baseline (386.766 us; speedup 1.0000x reference)
//
#include <hip/hip_runtime.h>

#define TT 1024
#define BB 2048
#define L2E2 2.8853900817779268f  // 2*log2(e)

typedef float v2f __attribute__((ext_vector_type(2)));

// DPP helpers ----------------------------------------------------------------
template <int CTRL>
__device__ __forceinline__ float dpp_add(float x) {
  int y = __builtin_amdgcn_update_dpp(0, __float_as_int(x), CTRL, 0xF, 0xF, true);
  return x + __int_as_float(y);
}
template <int CTRL>
__device__ __forceinline__ float dpp_mov(float x) {
  int y = __builtin_amdgcn_update_dpp(0, __float_as_int(x), CTRL, 0xF, 0xF, true);
  return __int_as_float(y);
}
// Sum within each aligned 8-lane group; result replicated in all 8 lanes.
__device__ __forceinline__ float sum8(float x) {
  x = dpp_add<0xB1>(x);   // quad_perm xor1
  x = dpp_add<0x4E>(x);   // quad_perm xor2
  x = dpp_add<0x141>(x);  // row_half_mirror (xor4 within 8)
  return x;
}
__device__ __forceinline__ float rdlane(float x, int l) {
  return __int_as_float(__builtin_amdgcn_readlane(__float_as_int(x), l));
}

// ---------------------------------------------------------------------------
// Fused RK4 scan + estC. R11 = R10 (best: 314us) + three micro-shaves:
//  (a) NA history delivery: row0 lanes already HOLD A (S==A there), so
//      NA = loRow ? S : bcast15(S) -- 1 DPP + select instead of 2 readlanes
//      + select. (R9's sound piece, isolated from the bad rcp-fold.)
//  (b) 8-step unroll: halves history-rotation movs + loop overhead.
//  (c) S-update re-assoc: S + (k1+k4)/6 + (k2+k3)/3 -- chain depth 4->3 on
//      the step-serial path (gates everything in the next step).
// Layout unchanged (per 32-half; e0 = lanes 0-31, e1 = 32-63):
//   row0: g0 = NN1/A (0-7),  g1 = NN1dup/Ad (8-15)
//   row1: g2 = NN3/C (16-23), g3 = NN2/B (24-31)
//   qr = row_ror:8(q): C<-P2, B<-P3;  m2 = row_bcast15(q): row1<-P1.
//   Combine: A/Ad: -P1(own). C: -P3(own)+P2(qr). B: -3P2(own)+P3(qr)+5/3P1(m2).
// estC: 1 neuron/lane (n=lane&31); sum16+bcast15 -> 32-sums in rows 1,3;
// comp3 stored from lanes 17/49. History in regs, 8-step unroll renaming.
__global__ __launch_bounds__(256) void phase1_kernel(
    const float* __restrict__ useq, const float* __restrict__ x0,
    const float* __restrict__ r1W0, const float* __restrict__ r1b0,
    const float* __restrict__ r1W1, const float* __restrict__ r1b1,
    const float* __restrict__ r2W0, const float* __restrict__ r2b0,
    const float* __restrict__ r2W1, const float* __restrict__ r2b1,
    const float* __restrict__ r3W0, const float* __restrict__ r3b0,
    const float* __restrict__ r3W1, const float* __restrict__ r3b1,
    const float* __restrict__ eW0, const float* __restrict__ eb0p,
    const float* __restrict__ eW1, const float* __restrict__ eb1p,
    float* __restrict__ out) {
  const int lane = threadIdx.x & 63;
  const int eh = lane >> 5;         // element half 0/1
  const int g = (lane >> 3) & 3;    // 8-lane group within half
  const int i = lane & 7;           // neuron lane within group
  const int e0 = __builtin_amdgcn_readfirstlane(
      (blockIdx.x * 4 + (threadIdx.x >> 6)) * 2);
  const int e = e0 + eh;            // per-lane element

  // Weights per group: g0,g1 -> NN1 (r1); g2 -> NN3 (r3); g3 -> NN2 (r2).
  const float* W0p = (g == 3) ? r2W0 : (g == 2) ? r3W0 : r1W0;
  const float* b0p = (g == 3) ? r2b0 : (g == 2) ? r3b0 : r1b0;
  const float* W1p = (g == 3) ? r2W1 : (g == 2) ? r3W1 : r1W1;

  const v2f w0s = {W0p[i] * L2E2, W0p[i + 8] * L2E2};
  const v2f b0s = {b0p[i] * L2E2, b0p[i + 8] * L2E2};
  const v2f iwn = {1.0f / (-2.0f * W1p[i]),
                   1.0f / (-2.0f * W1p[i + 8])};  // init-only divides

  float C1 = r1b1[0], C2 = r2b1[0], C3 = r3b1[0];
  for (int q = 0; q < 16; ++q) {
    C1 += r1W1[q];
    C2 += r2W1[q];
    C3 += r3W1[q];
  }
  const float caC = 0.2f - C1;
  const float cbC = -1.0f / 6.0f + (5.0f / 3.0f) * C1 - 3.0f * C2 + C3;
  const float ccC = -1.0f / 6.0f + C2 - C3;

  // Per-lane state & combine constants.
  const int strow = (g <= 1) ? 0 : (g == 2) ? 2 : 1;  // A,A,C,B
  const float cstBase = (g == 3) ? cbC : (g == 2) ? ccC : caC;
  const float uco = (g <= 1) ? 0.1f : 0.0f;
  const float c_own = (g == 3) ? -3.0f : -1.0f;
  const float c_qr = (g >= 2) ? 1.0f : 0.0f;
  const float c_m2 = (g == 3) ? (5.0f / 3.0f) : 0.0f;

  float S = x0[e * 15 + strow];

  // estC weights: neuron n = lane & 31.
  const int n = lane & 31;
  const float eb0v = eb0p[n] * L2E2;
  const float ew0 = eW0[0 * 32 + n] * L2E2;
  const float ew1 = eW0[1 * 32 + n] * L2E2;
  const float ew2 = eW0[2 * 32 + n] * L2E2;
  const float ew3 = eW0[3 * 32 + n] * L2E2;
  const float ew4 = eW0[4 * 32 + n] * L2E2;
  const float ew5 = eW0[5 * 32 + n] * L2E2;
  const float ew6 = eW0[6 * 32 + n] * L2E2;
  const float ew7 = eW0[7 * 32 + n] * L2E2;
  const float ew8 = eW0[8 * 32 + n] * L2E2;
  const float ew9 = eW0[9 * 32 + n] * L2E2;
  const float ew10 = eW0[10 * 32 + n] * L2E2;
  const float ew11 = eW0[11 * 32 + n] * L2E2;
  const float ew1n = -2.0f * eW1[n];
  float ebs = eb1p[0];
  for (int q = 0; q < 32; ++q) ebs += eW1[q];
  const float eb32 = ebs * 0.03125f;  // output bias folded per-lane

  // z-history (per-lane regs, own element's): pairs (A,B) oldest..newest.
  const float* zp = x0 + e * 15 + 3;
  float hA0 = zp[0], hB0 = zp[1], hA1 = zp[2], hB1 = zp[3];
  float hA2 = zp[4], hB2 = zp[5], hA3 = zp[6], hB3 = zp[7];
  float hU0 = zp[8], hU1 = zp[9], hU2 = zp[10], hU3 = zp[11];

  const float* up0 = useq + e0 * TT;        // uniform -> s_load prefetch
  const float* up1 = useq + (e0 + 1) * TT;
  // Store lanes per half: 0 -> comp0 (A), 24 -> comp1 (B), 16 -> comp2 (C),
  // 17 -> comp3 (estC).
  const int l31 = lane & 31;
  const int soff = (l31 == 0) ? 0 : (l31 == 24) ? 1 : (l31 == 16) ? 2 : 3;
  float* op = out + (size_t)e * TT * 4 + soff;
  const bool sflag = (l31 == 0) | (l31 == 24) | (l31 == 16) | (l31 == 17);
  const bool isE = (l31 == 17);
  const bool loRow = (l31 < 16);

#define STAGE(SS, KK)                                                     \
  {                                                                       \
    v2f h = __builtin_elementwise_fma(w0s, (v2f){(SS), (SS)}, b0s);       \
    h.x = __builtin_amdgcn_exp2f(h.x);                                    \
    h.y = __builtin_amdgcn_exp2f(h.y);                                    \
    h = __builtin_elementwise_fma(h, iwn, iwn);                           \
    float rv = __builtin_amdgcn_rcpf(h.x) + __builtin_amdgcn_rcpf(h.y);   \
    float q = sum8(rv);                                                   \
    float qr = dpp_mov<0x128>(q);   /* row_ror:8  (q-dependent) */        \
    float m2 = dpp_mov<0x142>(q);   /* row_bcast15 (q-dependent, par) */  \
    float t_ = fmaf(-0.1f, (SS), cstS);                                   \
    t_ = fmaf(c_own, q, t_);                                              \
    t_ = fmaf(c_qr, qr, t_);                                              \
    KK = fmaf(c_m2, m2, t_);                                              \
  }

// One time-step for both elements. estC first (independent chain -> fills
// RK stalls); history passed/produced by name (zero-cost rotation).
#define STEP(UA, UB, SC_, hA0_, hB0_, hA1_, hB1_, hA2_, hB2_, hA3_, hB3_, \
             hU0_, hU1_, hU2_, hU3_, NA_, NB_, NU_)                       \
  {                                                                       \
    float a_ = fmaf((hA0_), ew0, eb0v);                                   \
    a_ = fmaf((hB0_), ew1, a_);                                           \
    a_ = fmaf((hA1_), ew2, a_);                                           \
    a_ = fmaf((hB1_), ew3, a_);                                           \
    a_ = fmaf((hA2_), ew4, a_);                                           \
    a_ = fmaf((hB2_), ew5, a_);                                           \
    a_ = fmaf((hA3_), ew6, a_);                                           \
    a_ = fmaf((hB3_), ew7, a_);                                           \
    a_ = fmaf((hU0_), ew8, a_);                                           \
    a_ = fmaf((hU1_), ew9, a_);                                           \
    a_ = fmaf((hU2_), ew10, a_);                                          \
    a_ = fmaf((hU3_), ew11, a_);                                          \
    float er_ = __builtin_amdgcn_rcpf(__builtin_amdgcn_exp2f(a_) + 1.0f); \
    float ps_ = fmaf(ew1n, er_, eb32);                                    \
    ps_ = dpp_add<0xB1>(ps_);                                             \
    ps_ = dpp_add<0x4E>(ps_);                                             \
    ps_ = dpp_add<0x141>(ps_);                                            \
    ps_ = dpp_add<0x140>(ps_);   /* per-16-row sums */                    \
    ps_ = dpp_add<0x142>(ps_);   /* rows 1,3: full 32-neuron sums */      \
    NA_ = loRow ? S : dpp_mov<0x142>(S);  /* row0 holds A; bcast15 up */  \
    const float sBa_ = rdlane(S, 24);                                     \
    const float sBb_ = rdlane(S, 56);                                     \
    NB_ = eh ? sBb_ : sBa_;                                               \
    const float usel_ = eh ? (UB) : (UA);                                 \
    NU_ = usel_;                                                          \
    const float cstS = fmaf(uco, usel_, cstBase);                         \
    SC_ = isE ? ps_ : S;                                                  \
    float k1, k2, k3, k4;                                                 \
    STAGE(S, k1)                                                          \
    float s2 = fmaf(0.5f, k1, S);                                         \
    STAGE(s2, k2)                                                         \
    float s3 = fmaf(0.5f, k2, S);                                         \
    STAGE(s3, k3)                                                         \
    float s4 = S + k3;                                                    \
    STAGE(s4, k4)                                                         \
    S = fmaf(1.0f / 6.0f, k1 + k4, fmaf(1.0f / 3.0f, k2 + k3, S));        \
  }

  float4 ca0 = *(const float4*)(up0);
  float4 ca1 = *(const float4*)(up0 + 4);
  float4 cb0 = *(const float4*)(up1);
  float4 cb1 = *(const float4*)(up1 + 4);

  for (int t0 = 0; t0 < TT; t0 += 8) {
    const int tn = (t0 + 8 <= TT - 8) ? (t0 + 8) : (TT - 8);
    const float4 na0 = *(const float4*)(up0 + tn);
    const float4 na1 = *(const float4*)(up0 + tn + 4);
    const float4 nb0 = *(const float4*)(up1 + tn);
    const float4 nb1 = *(const float4*)(up1 + tn + 4);

    float sc0, sc1, sc2, sc3, sc4, sc5, sc6, sc7;
    float A4, B4, U4, A5, B5, U5, A6, B6, U6, A7, B7, U7;
    float A8, B8, U8, A9, B9, U9, A10, B10, U10, A11, B11, U11;
    STEP(ca0.x, cb0.x, sc0, hA0, hB0, hA1, hB1, hA2, hB2, hA3, hB3,
         hU0, hU1, hU2, hU3, A4, B4, U4)
    STEP(ca0.y, cb0.y, sc1, hA1, hB1, hA2, hB2, hA3, hB3, A4, B4,
         hU1, hU2, hU3, U4, A5, B5, U5)
    STEP(ca0.z, cb0.z, sc2, hA2, hB2, hA3, hB3, A4, B4, A5, B5,
         hU2, hU3, U4, U5, A6, B6, U6)
    STEP(ca0.w, cb0.w, sc3, hA3, hB3, A4, B4, A5, B5, A6, B6,
         hU3, U4, U5, U6, A7, B7, U7)
    STEP(ca1.x, cb1.x, sc4, A4, B4, A5, B5, A6, B6, A7, B7,
         U4, U5, U6, U7, A8, B8, U8)
    STEP(ca1.y, cb1.y, sc5, A5, B5, A6, B6, A7, B7, A8, B8,
         U5, U6, U7, U8, A9, B9, U9)
    STEP(ca1.z, cb1.z, sc6, A6, B6, A7, B7, A8, B8, A9, B9,
         U6, U7, U8, U9, A10, B10, U10)
    STEP(ca1.w, cb1.w, sc7, A7, B7, A8, B8, A9, B9, A10, B10,
         U7, U8, U9, U10, A11, B11, U11)

    // Batched stores: lanes {0,24,16,17} (e0) and +32 (e1) write comps
    // {0,1,2,3} for 8 steps.
    if (sflag) {
      float* p = op + t0 * 4;
      p[0] = sc0;   p[4] = sc1;   p[8] = sc2;   p[12] = sc3;
      p[16] = sc4;  p[20] = sc5;  p[24] = sc6;  p[28] = sc7;
    }

    hA0 = A8;  hB0 = B8;  hA1 = A9;  hB1 = B9;
    hA2 = A10; hB2 = B10; hA3 = A11; hB3 = B11;
    hU0 = U8;  hU1 = U9;  hU2 = U10; hU3 = U11;

    ca0 = na0; ca1 = na1; cb0 = nb0; cb1 = nb1;
  }
#undef STEP
#undef STAGE
}

// ---------------------------------------------------------------------------
extern "C" void kernel_launch(void* const* d_in, const int* in_sizes, int n_in,
                              void* d_out, int out_size, void* d_ws,
                              size_t ws_size, hipStream_t stream) {
  const float* useq = (const float*)d_in[0];
  const float* x0 = (const float*)d_in[1];
  float* out = (float*)d_out;

  phase1_kernel<<<BB / 8, 256, 0, stream>>>(
      useq, x0,
      (const float*)d_in[2], (const float*)d_in[3], (const float*)d_in[4],
      (const float*)d_in[5], (const float*)d_in[6], (const float*)d_in[7],
      (const float*)d_in[8], (const float*)d_in[9], (const float*)d_in[10],
      (const float*)d_in[11], (const float*)d_in[12], (const float*)d_in[13],
      (const float*)d_in[14], (const float*)d_in[15], (const float*)d_in[16],
      (const float*)d_in[17], out);
}

// Round 12
// 381.928 us; speedup vs baseline: 1.0127x; 1.0127x over previous
//
#include <hip/hip_runtime.h>

#define TT 1024
#define BB 2048
#define L2E2 2.8853900817779268f  // 2*log2(e)

typedef float v2f __attribute__((ext_vector_type(2)));

// DPP helpers ----------------------------------------------------------------
template <int CTRL>
__device__ __forceinline__ float dpp_add(float x) {
  int y = __builtin_amdgcn_update_dpp(0, __float_as_int(x), CTRL, 0xF, 0xF, true);
  return x + __int_as_float(y);
}
template <int CTRL>
__device__ __forceinline__ float dpp_mov(float x) {
  int y = __builtin_amdgcn_update_dpp(0, __float_as_int(x), CTRL, 0xF, 0xF, true);
  return __int_as_float(y);
}
// Sum within each aligned 8-lane group; result replicated in all 8 lanes.
__device__ __forceinline__ float sum8(float x) {
  x = dpp_add<0xB1>(x);   // quad_perm xor1
  x = dpp_add<0x4E>(x);   // quad_perm xor2
  x = dpp_add<0x141>(x);  // row_half_mirror (xor4 within 8)
  return x;
}
__device__ __forceinline__ float rdlane(float x, int l) {
  return __int_as_float(__builtin_amdgcn_readlane(__float_as_int(x), l));
}

// ---------------------------------------------------------------------------
// Fused RK4 scan + estC. R12 = EXACT REVERT to R10 (best: 314us phase1,
// 384.0us total, absmax 0.125). R11's bundle (NA-bcast15 + 8-step unroll +
// S-update re-assoc) regressed to 319us and drifted absmax to 0.1328 -> the
// re-assoc sits on the numerically-sensitive serial scan path (same lesson
// as R9's rcp-fold). This structure is at its measured practical floor:
// R8-R11 = {325, 365, 314, 319}; all perturbations land within +/-2% or
// regress. ~530 busy-cy/SIMD-step (72% VALUBusy), remaining 28% is serial
// chain exposure with no independent work left to fill (estC already fused);
// occupancy structurally pinned at 1 wave/SIMD (2048 elements / 2 per wave).
// Layout (per 32-half; e0 = lanes 0-31, e1 = 32-63):
//   row0: g0 = NN1/A (0-7),  g1 = NN1dup/Ad (8-15)
//   row1: g2 = NN3/C (16-23), g3 = NN2/B (24-31)
//   qr = row_ror:8(q): C<-P2, B<-P3;  m2 = row_bcast15(q): row1<-P1.
//   Combine: A/Ad: -P1(own). C: -P3(own)+P2(qr). B: -3P2(own)+P3(qr)+5/3P1(m2).
// estC: 1 neuron/lane (n=lane&31); sum16+bcast15 -> 32-sums in rows 1,3;
// comp3 stored from lanes 17/49. History in regs, 4-step unroll renaming.
__global__ __launch_bounds__(256) void phase1_kernel(
    const float* __restrict__ useq, const float* __restrict__ x0,
    const float* __restrict__ r1W0, const float* __restrict__ r1b0,
    const float* __restrict__ r1W1, const float* __restrict__ r1b1,
    const float* __restrict__ r2W0, const float* __restrict__ r2b0,
    const float* __restrict__ r2W1, const float* __restrict__ r2b1,
    const float* __restrict__ r3W0, const float* __restrict__ r3b0,
    const float* __restrict__ r3W1, const float* __restrict__ r3b1,
    const float* __restrict__ eW0, const float* __restrict__ eb0p,
    const float* __restrict__ eW1, const float* __restrict__ eb1p,
    float* __restrict__ out) {
  const int lane = threadIdx.x & 63;
  const int eh = lane >> 5;         // element half 0/1
  const int g = (lane >> 3) & 3;    // 8-lane group within half
  const int i = lane & 7;           // neuron lane within group
  const int e0 = __builtin_amdgcn_readfirstlane(
      (blockIdx.x * 4 + (threadIdx.x >> 6)) * 2);
  const int e = e0 + eh;            // per-lane element

  // Weights per group: g0,g1 -> NN1 (r1); g2 -> NN3 (r3); g3 -> NN2 (r2).
  const float* W0p = (g == 3) ? r2W0 : (g == 2) ? r3W0 : r1W0;
  const float* b0p = (g == 3) ? r2b0 : (g == 2) ? r3b0 : r1b0;
  const float* W1p = (g == 3) ? r2W1 : (g == 2) ? r3W1 : r1W1;

  const v2f w0s = {W0p[i] * L2E2, W0p[i + 8] * L2E2};
  const v2f b0s = {b0p[i] * L2E2, b0p[i + 8] * L2E2};
  const v2f iwn = {1.0f / (-2.0f * W1p[i]),
                   1.0f / (-2.0f * W1p[i + 8])};  // init-only divides

  float C1 = r1b1[0], C2 = r2b1[0], C3 = r3b1[0];
  for (int q = 0; q < 16; ++q) {
    C1 += r1W1[q];
    C2 += r2W1[q];
    C3 += r3W1[q];
  }
  const float caC = 0.2f - C1;
  const float cbC = -1.0f / 6.0f + (5.0f / 3.0f) * C1 - 3.0f * C2 + C3;
  const float ccC = -1.0f / 6.0f + C2 - C3;

  // Per-lane state & combine constants.
  const int strow = (g <= 1) ? 0 : (g == 2) ? 2 : 1;  // A,A,C,B
  const float cstBase = (g == 3) ? cbC : (g == 2) ? ccC : caC;
  const float uco = (g <= 1) ? 0.1f : 0.0f;
  const float c_own = (g == 3) ? -3.0f : -1.0f;
  const float c_qr = (g >= 2) ? 1.0f : 0.0f;
  const float c_m2 = (g == 3) ? (5.0f / 3.0f) : 0.0f;

  float S = x0[e * 15 + strow];

  // estC weights: neuron n = lane & 31.
  const int n = lane & 31;
  const float eb0v = eb0p[n] * L2E2;
  const float ew0 = eW0[0 * 32 + n] * L2E2;
  const float ew1 = eW0[1 * 32 + n] * L2E2;
  const float ew2 = eW0[2 * 32 + n] * L2E2;
  const float ew3 = eW0[3 * 32 + n] * L2E2;
  const float ew4 = eW0[4 * 32 + n] * L2E2;
  const float ew5 = eW0[5 * 32 + n] * L2E2;
  const float ew6 = eW0[6 * 32 + n] * L2E2;
  const float ew7 = eW0[7 * 32 + n] * L2E2;
  const float ew8 = eW0[8 * 32 + n] * L2E2;
  const float ew9 = eW0[9 * 32 + n] * L2E2;
  const float ew10 = eW0[10 * 32 + n] * L2E2;
  const float ew11 = eW0[11 * 32 + n] * L2E2;
  const float ew1n = -2.0f * eW1[n];
  float ebs = eb1p[0];
  for (int q = 0; q < 32; ++q) ebs += eW1[q];
  const float eb32 = ebs * 0.03125f;  // output bias folded per-lane

  // z-history (per-lane regs, own element's): pairs (A,B) oldest..newest.
  const float* zp = x0 + e * 15 + 3;
  float hA0 = zp[0], hB0 = zp[1], hA1 = zp[2], hB1 = zp[3];
  float hA2 = zp[4], hB2 = zp[5], hA3 = zp[6], hB3 = zp[7];
  float hU0 = zp[8], hU1 = zp[9], hU2 = zp[10], hU3 = zp[11];

  const float* up0 = useq + e0 * TT;        // uniform -> s_load prefetch
  const float* up1 = useq + (e0 + 1) * TT;
  // Store lanes per half: 0 -> comp0 (A), 24 -> comp1 (B), 16 -> comp2 (C),
  // 17 -> comp3 (estC).
  const int l31 = lane & 31;
  const int soff = (l31 == 0) ? 0 : (l31 == 24) ? 1 : (l31 == 16) ? 2 : 3;
  float* op = out + (size_t)e * TT * 4 + soff;
  const bool sflag = (l31 == 0) | (l31 == 24) | (l31 == 16) | (l31 == 17);
  const bool isE = (l31 == 17);

#define STAGE(SS, KK)                                                     \
  {                                                                       \
    v2f h = __builtin_elementwise_fma(w0s, (v2f){(SS), (SS)}, b0s);       \
    h.x = __builtin_amdgcn_exp2f(h.x);                                    \
    h.y = __builtin_amdgcn_exp2f(h.y);                                    \
    h = __builtin_elementwise_fma(h, iwn, iwn);                           \
    float rv = __builtin_amdgcn_rcpf(h.x) + __builtin_amdgcn_rcpf(h.y);   \
    float q = sum8(rv);                                                   \
    float qr = dpp_mov<0x128>(q);   /* row_ror:8  (q-dependent) */        \
    float m2 = dpp_mov<0x142>(q);   /* row_bcast15 (q-dependent, par) */  \
    float t_ = fmaf(-0.1f, (SS), cstS);                                   \
    t_ = fmaf(c_own, q, t_);                                              \
    t_ = fmaf(c_qr, qr, t_);                                              \
    KK = fmaf(c_m2, m2, t_);                                              \
  }

// One time-step for both elements. estC first (independent chain -> fills
// RK stalls); history passed/produced by name (zero-cost rotation).
#define STEP(UA, UB, SC_, hA0_, hB0_, hA1_, hB1_, hA2_, hB2_, hA3_, hB3_, \
             hU0_, hU1_, hU2_, hU3_, NA_, NB_, NU_)                       \
  {                                                                       \
    float a_ = fmaf((hA0_), ew0, eb0v);                                   \
    a_ = fmaf((hB0_), ew1, a_);                                           \
    a_ = fmaf((hA1_), ew2, a_);                                           \
    a_ = fmaf((hB1_), ew3, a_);                                           \
    a_ = fmaf((hA2_), ew4, a_);                                           \
    a_ = fmaf((hB2_), ew5, a_);                                           \
    a_ = fmaf((hA3_), ew6, a_);                                           \
    a_ = fmaf((hB3_), ew7, a_);                                           \
    a_ = fmaf((hU0_), ew8, a_);                                           \
    a_ = fmaf((hU1_), ew9, a_);                                           \
    a_ = fmaf((hU2_), ew10, a_);                                          \
    a_ = fmaf((hU3_), ew11, a_);                                          \
    float er_ = __builtin_amdgcn_rcpf(__builtin_amdgcn_exp2f(a_) + 1.0f); \
    float ps_ = fmaf(ew1n, er_, eb32);                                    \
    ps_ = dpp_add<0xB1>(ps_);                                             \
    ps_ = dpp_add<0x4E>(ps_);                                             \
    ps_ = dpp_add<0x141>(ps_);                                            \
    ps_ = dpp_add<0x140>(ps_);   /* per-16-row sums */                    \
    ps_ = dpp_add<0x142>(ps_);   /* rows 1,3: full 32-neuron sums */      \
    const float sAa_ = rdlane(S, 0);                                      \
    const float sBa_ = rdlane(S, 24);                                     \
    const float sAb_ = rdlane(S, 32);                                     \
    const float sBb_ = rdlane(S, 56);                                     \
    NA_ = eh ? sAb_ : sAa_;                                               \
    NB_ = eh ? sBb_ : sBa_;                                               \
    const float usel_ = eh ? (UB) : (UA);                                 \
    NU_ = usel_;                                                          \
    const float cstS = fmaf(uco, usel_, cstBase);                         \
    SC_ = isE ? ps_ : S;                                                  \
    float k1, k2, k3, k4;                                                 \
    STAGE(S, k1)                                                          \
    float s2 = fmaf(0.5f, k1, S);                                         \
    STAGE(s2, k2)                                                         \
    float s3 = fmaf(0.5f, k2, S);                                         \
    STAGE(s3, k3)                                                         \
    float s4 = S + k3;                                                    \
    STAGE(s4, k4)                                                         \
    S = fmaf(1.0f / 6.0f, fmaf(2.0f, k2 + k3, k1) + k4, S);               \
  }

  float4 cura = *(const float4*)(up0);
  float4 curb = *(const float4*)(up1);

  for (int t0 = 0; t0 < TT; t0 += 4) {
    const int tn = (t0 + 4 <= TT - 4) ? (t0 + 4) : (TT - 4);
    const float4 naa = *(const float4*)(up0 + tn);
    const float4 nab = *(const float4*)(up1 + tn);

    float sc0, sc1, sc2, sc3;
    float A4, B4, U4, A5, B5, U5, A6, B6, U6, A7, B7, U7;
    STEP(cura.x, curb.x, sc0, hA0, hB0, hA1, hB1, hA2, hB2, hA3, hB3,
         hU0, hU1, hU2, hU3, A4, B4, U4)
    STEP(cura.y, curb.y, sc1, hA1, hB1, hA2, hB2, hA3, hB3, A4, B4,
         hU1, hU2, hU3, U4, A5, B5, U5)
    STEP(cura.z, curb.z, sc2, hA2, hB2, hA3, hB3, A4, B4, A5, B5,
         hU2, hU3, U4, U5, A6, B6, U6)
    STEP(cura.w, curb.w, sc3, hA3, hB3, A4, B4, A5, B5, A6, B6,
         hU3, U4, U5, U6, A7, B7, U7)

    // Batched stores: lanes {0,24,16,17} (e0) and +32 (e1) write comps
    // {0,1,2,3} for 4 steps.
    if (sflag) {
      float* p = op + t0 * 4;
      p[0] = sc0;  p[4] = sc1;  p[8] = sc2;  p[12] = sc3;
    }

    hA0 = A4; hB0 = B4; hA1 = A5; hB1 = B5;
    hA2 = A6; hB2 = B6; hA3 = A7; hB3 = B7;
    hU0 = U4; hU1 = U5; hU2 = U6; hU3 = U7;

    cura = naa;
    curb = nab;
  }
#undef STEP
#undef STAGE
}

// ---------------------------------------------------------------------------
extern "C" void kernel_launch(void* const* d_in, const int* in_sizes, int n_in,
                              void* d_out, int out_size, void* d_ws,
                              size_t ws_size, hipStream_t stream) {
  const float* useq = (const float*)d_in[0];
  const float* x0 = (const float*)d_in[1];
  float* out = (float*)d_out;

  phase1_kernel<<<BB / 8, 256, 0, stream>>>(
      useq, x0,
      (const float*)d_in[2], (const float*)d_in[3], (const float*)d_in[4],
      (const float*)d_in[5], (const float*)d_in[6], (const float*)d_in[7],
      (const float*)d_in[8], (const float*)d_in[9], (const float*)d_in[10],
      (const float*)d_in[11], (const float*)d_in[12], (const float*)d_in[13],
      (const float*)d_in[14], (const float*)d_in[15], (const float*)d_in[16],
      (const float*)d_in[17], out);
}